// Round 6
// baseline (38675.565 us; speedup 1.0000x reference)
//
#include <hip/hip_runtime.h>
#include <stdint.h>

#define N_NODES 10000
#define E_EDGES 640000
#define D_IN    256
#define H_DIM   512
#define RING    64    // chunk ring depth (steps)

typedef unsigned short ushort_t;
typedef unsigned int   uint32;
typedef unsigned long long u64;

// ---------- bf16 helpers (pre0 internal storage only) ----------
__device__ __forceinline__ float bf2f(ushort_t u) {
  union { uint32 i; float f; } v; v.i = ((uint32)u) << 16; return v.f;
}
__device__ __forceinline__ ushort_t f2bf(float f) {
  union { float f; uint32 i; } v; v.f = f;
  uint32 x = v.i;
  uint32 r = (x + 0x7FFFu + ((x >> 16) & 1u)) >> 16;
  return (ushort_t)r;
}

// ---------- fast gate math ----------
__device__ __forceinline__ float sigmoid_f(float x) {
  return 1.f / (1.f + __expf(-x));
}
__device__ __forceinline__ float tanh_f(float x) {
  x = fminf(10.f, fmaxf(-10.f, x));
  float e2 = __expf(2.f * x);
  return (e2 - 1.f) / (e2 + 1.f);
}

// ---------- fused data+flag 8B chunks: [h fp32 | step+1] via relaxed agent atomics ----------
__device__ __forceinline__ u64 ld_c8(const u64* p) {
  return __hip_atomic_load(p, __ATOMIC_RELAXED, __HIP_MEMORY_SCOPE_AGENT);
}
__device__ __forceinline__ void st_c8(u64* p, float h, int flag) {
  u64 u = ((u64)(uint32)flag << 32) | (u64)__float_as_uint(h);
  __hip_atomic_store(p, u, __ATOMIC_RELAXED, __HIP_MEMORY_SCOPE_AGENT);
}

// ---------- workspace zero (control region only: 57344 B) ----------
__global__ void k_zero(int* p) {
  p[blockIdx.x * 256 + threadIdx.x] = 0;   // 56 blocks -> 14336 words
}

// ---------- edge_index dtype detector ----------
__global__ void k_detect(const int* eb, int* ctrl) {
  int v = eb[2 * (int)threadIdx.x + 1];
  if (v != 0) atomicOr(ctrl, 1);           // 1 => int32, 0 => int64
}

__device__ __forceinline__ int edge_src(const int* eb, int flag, int e) {
  return flag ? eb[e] : eb[2 * e];
}
__device__ __forceinline__ int edge_dst(const int* eb, int flag, int e) {
  return flag ? eb[E_EDGES + e] : eb[2 * (E_EDGES + e)];
}

// ---------- GIN: degree count ----------
__global__ __launch_bounds__(256) void k_count(const int* eb, const int* ctrl, int* deg) {
  int e = blockIdx.x * 256 + threadIdx.x;
  if (e >= E_EDGES) return;
  int flag = ctrl[0];
  atomicAdd(&deg[edge_dst(eb, flag, e)], 1);
}

// ---------- GIN: exclusive prefix sum ----------
__global__ __launch_bounds__(1024) void k_prefix(const int* deg, int* off, int* cursor) {
  __shared__ int sums[1024];
  int tid = threadIdx.x;
  const int PER = 10;
  int base = tid * PER;
  int loc[PER];
  int s = 0;
  for (int i = 0; i < PER; i++) {
    int idx = base + i;
    int v = (idx < N_NODES) ? deg[idx] : 0;
    loc[i] = s; s += v;
  }
  sums[tid] = s;
  __syncthreads();
  for (int d = 1; d < 1024; d <<= 1) {
    int v = (tid >= d) ? sums[tid - d] : 0;
    __syncthreads();
    sums[tid] += v;
    __syncthreads();
  }
  int excl = (tid == 0) ? 0 : sums[tid - 1];
  for (int i = 0; i < PER; i++) {
    int idx = base + i;
    if (idx < N_NODES) { int o = excl + loc[i]; off[idx] = o; cursor[idx] = o; }
  }
  if (tid == 1023) off[N_NODES] = sums[1023];
}

// ---------- GIN: CSR fill ----------
__global__ __launch_bounds__(256) void k_fill(const int* eb, const int* ctrl, int* cursor, int* csr) {
  int e = blockIdx.x * 256 + threadIdx.x;
  if (e >= E_EDGES) return;
  int flag = ctrl[0];
  int d = edge_dst(eb, flag, e);
  int s = edge_src(eb, flag, e);
  int slot = atomicAdd(&cursor[d], 1);
  csr[slot] = s;
}

// ---------- GIN: aggregate ----------
__global__ __launch_bounds__(256) void k_agg(const float* x, const int* off, const int* csr, float* h0) {
  int node = blockIdx.x;
  int f = threadIdx.x;
  float acc = x[(size_t)node * D_IN + f];
  int a = off[node], b = off[node + 1];
  for (int e = a; e < b; e++) {
    int s = csr[e];
    acc += x[(size_t)s * D_IN + f];
  }
  h0[(size_t)node * D_IN + f] = acc;
}

// ---------- fp32 tiled GEMM ----------
template<int KTOT, bool RELU, bool OUTBF16, bool TWOBIAS>
__global__ __launch_bounds__(256) void k_gemm(const float* __restrict__ A,
                                              const float* __restrict__ W,
                                              const float* __restrict__ bias1,
                                              const float* __restrict__ bias2,
                                              void* __restrict__ Cout, int M, int Ncols) {
  __shared__ float As[16][65];
  __shared__ float Ws[16][65];
  int tid = threadIdx.x;
  int tx = tid & 15, ty = tid >> 4;
  int by = blockIdx.x, bn = blockIdx.y;
  int lr  = tid >> 2;
  int lk4 = (tid & 3) * 4;
  float acc[4][4];
  #pragma unroll
  for (int i = 0; i < 4; i++)
    #pragma unroll
    for (int j = 0; j < 4; j++) acc[i][j] = 0.f;

  for (int k0 = 0; k0 < KTOT; k0 += 16) {
    int arow = by * 64 + lr;
    float4 av = make_float4(0.f, 0.f, 0.f, 0.f);
    if (arow < M) av = *(const float4*)(A + (size_t)arow * KTOT + k0 + lk4);
    As[lk4 + 0][lr] = av.x; As[lk4 + 1][lr] = av.y;
    As[lk4 + 2][lr] = av.z; As[lk4 + 3][lr] = av.w;
    float4 wv = *(const float4*)(W + (size_t)(bn * 64 + lr) * KTOT + k0 + lk4);
    Ws[lk4 + 0][lr] = wv.x; Ws[lk4 + 1][lr] = wv.y;
    Ws[lk4 + 2][lr] = wv.z; Ws[lk4 + 3][lr] = wv.w;
    __syncthreads();
    #pragma unroll
    for (int k = 0; k < 16; k++) {
      float a0 = As[k][ty], a1 = As[k][16 + ty], a2 = As[k][32 + ty], a3 = As[k][48 + ty];
      float w0 = Ws[k][tx], w1 = Ws[k][16 + tx], w2 = Ws[k][32 + tx], w3 = Ws[k][48 + tx];
      acc[0][0] += a0 * w0; acc[0][1] += a0 * w1; acc[0][2] += a0 * w2; acc[0][3] += a0 * w3;
      acc[1][0] += a1 * w0; acc[1][1] += a1 * w1; acc[1][2] += a1 * w2; acc[1][3] += a1 * w3;
      acc[2][0] += a2 * w0; acc[2][1] += a2 * w1; acc[2][2] += a2 * w2; acc[2][3] += a2 * w3;
      acc[3][0] += a3 * w0; acc[3][1] += a3 * w1; acc[3][2] += a3 * w2; acc[3][3] += a3 * w3;
    }
    __syncthreads();
  }
  float* Cf = (float*)Cout;
  ushort_t* Cb = (ushort_t*)Cout;
  #pragma unroll
  for (int i = 0; i < 4; i++) {
    int row = by * 64 + 16 * i + ty;
    if (row >= M) continue;
    #pragma unroll
    for (int j = 0; j < 4; j++) {
      int col = bn * 64 + 16 * j + tx;
      float b = bias1[col];
      if (TWOBIAS) b += bias2[col];
      float v = acc[i][j] + b;
      if (RELU) v = fmaxf(v, 0.f);
      if (OUTBF16) Cb[(size_t)row * Ncols + col] = f2bf(v);
      else         Cf[(size_t)row * Ncols + col] = v;
    }
  }
}

// ---------- BatchNorm ----------
__global__ __launch_bounds__(256) void k_bnstats(const float* y2, float* colsum, float* colsumsq) {
  int b = blockIdx.x, tid = threadIdx.x;
  int r0 = b * 64, r1 = min(r0 + 64, N_NODES);
  float s0 = 0, q0 = 0, s1 = 0, q1 = 0;
  for (int r = r0; r < r1; r++) {
    float v0 = y2[(size_t)r * H_DIM + tid];
    float v1 = y2[(size_t)r * H_DIM + tid + 256];
    s0 += v0; q0 += v0 * v0; s1 += v1; q1 += v1 * v1;
  }
  atomicAdd(&colsum[tid], s0);        atomicAdd(&colsumsq[tid], q0);
  atomicAdd(&colsum[tid + 256], s1);  atomicAdd(&colsumsq[tid + 256], q1);
}

__global__ __launch_bounds__(256) void k_bnfin(float* colsum, float* colsumsq,
                                               const float* gamma, const float* beta) {
  int c = blockIdx.x * 256 + threadIdx.x;
  if (c >= H_DIM) return;
  float mean = colsum[c] * (1.f / N_NODES);
  float var  = colsumsq[c] * (1.f / N_NODES) - mean * mean;
  float sc = gamma[c] * rsqrtf(var + 1e-5f);
  float sh = beta[c] - mean * sc;
  colsum[c] = sc; colsumsq[c] = sh;
}

__global__ __launch_bounds__(256) void k_bnapply(float* y2, const float* sc, const float* sh) {
  size_t i = (size_t)blockIdx.x * 256 + threadIdx.x;
  int c = (int)(i & (H_DIM - 1));
  float v = y2[i] * sc[c] + sh[c];
  y2[i] = v > 0.f ? v : 0.f;
}

// ---------- persistent single-wave dataflow LSTM ----------
// 512 WGs of 64 threads, 0 LDS, 0 __syncthreads. WGs 0..255: layer0 units
// (2wg,2wg+1). WGs 256..511: layer1 units (2wg1,2wg1+1). Each lane gathers 8
// contiguous h chunks (its dot segment); row dots combined via 6-level
// __shfl_xor allreduce (exec-mask divergence in the poll loop IS the arrival
// barrier). Gates computed redundantly on all lanes; lanes 0-1 store chunks.
__global__ __launch_bounds__(64, 1) void k_lstm(const ushort_t* pre0, const float* w_hh0,
                                              const float* w_ih1, const float* w_hh1,
                                              const float* b_ih1, const float* b_hh1,
                                              u64* hs0c, u64* hs1c, float* hs1p,
                                              int* flags1, float* dout) {
  int lane = threadIdx.x;          // 0..63
  int wg = blockIdx.x;             // 0..511

  if (wg < 256) {
    // ---------------- layer 0: units (2wg, 2wg+1) ----------------
    int ubase = wg * 2;
    float wr[8][8];                // rows rr = gate*2 + u
    #pragma unroll
    for (int rr = 0; rr < 8; rr++) {
      int g = rr >> 1, u = rr & 1;
      const float* src = w_hh0 + (size_t)(g * H_DIM + ubase + u) * H_DIM + lane * 8;
      float4 a = *(const float4*)(src);
      float4 b = *(const float4*)(src + 4);
      wr[rr][0] = a.x; wr[rr][1] = a.y; wr[rr][2] = a.z; wr[rr][3] = a.w;
      wr[rr][4] = b.x; wr[rr][5] = b.y; wr[rr][6] = b.z; wr[rr][7] = b.w;
    }
    uint32 ppk[4];                 // pre0 bf16 pair per gate for step t (all lanes same)
    #pragma unroll
    for (int g = 0; g < 4; g++)
      ppk[g] = *(const uint32*)(pre0 + (size_t)0 * 2048 + g * H_DIM + ubase);
    float c0 = 0.f, c1 = 0.f;

    for (int t = 0; t < N_NODES; t++) {
      float h[8];
      if (t > 0) {
        const u64* base = hs0c + (size_t)((t - 1) & (RING - 1)) * 512 + lane * 8;
        u64 cc[8]; int guard = 0;
        for (;;) {
          #pragma unroll
          for (int j = 0; j < 8; j++) cc[j] = ld_c8(base + j);
          bool ok = true;
          #pragma unroll
          for (int j = 0; j < 8; j++) ok = ok && ((int)(cc[j] >> 32) == t);
          if (ok || ++guard > 50000000) break;
        }
        #pragma unroll
        for (int j = 0; j < 8; j++) h[j] = __uint_as_float((uint32)cc[j]);
      } else {
        #pragma unroll
        for (int j = 0; j < 8; j++) h[j] = 0.f;
      }
      uint32 ppn[4];               // prefetch next step's pre0 (plain cached loads)
      if (t + 1 < N_NODES) {
        #pragma unroll
        for (int g = 0; g < 4; g++)
          ppn[g] = *(const uint32*)(pre0 + (size_t)(t + 1) * 2048 + g * H_DIM + ubase);
      } else {
        #pragma unroll
        for (int g = 0; g < 4; g++) ppn[g] = 0;
      }
      float d[8];
      if (t > 0) {
        #pragma unroll
        for (int rr = 0; rr < 8; rr++) {
          float s = 0.f;
          #pragma unroll
          for (int j = 0; j < 8; j++) s += wr[rr][j] * h[j];
          d[rr] = s;
        }
        #pragma unroll
        for (int rr = 0; rr < 8; rr++) {
          #pragma unroll
          for (int off = 1; off < 64; off <<= 1) d[rr] += __shfl_xor(d[rr], off, 64);
        }
      } else {
        #pragma unroll
        for (int rr = 0; rr < 8; rr++) d[rr] = 0.f;
      }
      // gates (redundant on all lanes); unit u pre = bf16 half u of ppk[g]
      float h0v, h1v;
      {
        float gi = d[0] + bf2f((ushort_t)(ppk[0] & 0xFFFF));
        float gf = d[2] + bf2f((ushort_t)(ppk[1] & 0xFFFF));
        float gg = d[4] + bf2f((ushort_t)(ppk[2] & 0xFFFF));
        float go = d[6] + bf2f((ushort_t)(ppk[3] & 0xFFFF));
        float ii = sigmoid_f(gi), ff = sigmoid_f(gf), g2 = tanh_f(gg), oo = sigmoid_f(go);
        c0 = ff * c0 + ii * g2;
        h0v = oo * tanh_f(c0);
      }
      {
        float gi = d[1] + bf2f((ushort_t)(ppk[0] >> 16));
        float gf = d[3] + bf2f((ushort_t)(ppk[1] >> 16));
        float gg = d[5] + bf2f((ushort_t)(ppk[2] >> 16));
        float go = d[7] + bf2f((ushort_t)(ppk[3] >> 16));
        float ii = sigmoid_f(gi), ff = sigmoid_f(gf), g2 = tanh_f(gg), oo = sigmoid_f(go);
        c1 = ff * c1 + ii * g2;
        h1v = oo * tanh_f(c1);
      }
      if (lane < 2) {
        float hv = lane ? h1v : h0v;
        st_c8(hs0c + (size_t)(t & (RING - 1)) * 512 + ubase + lane, hv, t + 1);
        if (t == N_NODES - 1) {
          dout[10000 + ubase + lane] = hv;
          dout[11024 + ubase + lane] = lane ? c1 : c0;
        }
      }
      // ring back-pressure vs layer1 every 16 steps: flags1[*] >= t-32
      if ((t & 15) == 0 && t >= 48) {
        int tgt = t - 32;
        int g2_ = 0;
        for (;;) {
          int m0 = __hip_atomic_load(&flags1[lane * 4 + 0], __ATOMIC_RELAXED, __HIP_MEMORY_SCOPE_AGENT);
          int m1 = __hip_atomic_load(&flags1[lane * 4 + 1], __ATOMIC_RELAXED, __HIP_MEMORY_SCOPE_AGENT);
          int m2 = __hip_atomic_load(&flags1[lane * 4 + 2], __ATOMIC_RELAXED, __HIP_MEMORY_SCOPE_AGENT);
          int m3 = __hip_atomic_load(&flags1[lane * 4 + 3], __ATOMIC_RELAXED, __HIP_MEMORY_SCOPE_AGENT);
          bool myok = (m0 >= tgt) && (m1 >= tgt) && (m2 >= tgt) && (m3 >= tgt);
          if (__all(myok) || ++g2_ > 5000000) break;
          __builtin_amdgcn_s_sleep(1);
        }
      }
      #pragma unroll
      for (int g = 0; g < 4; g++) ppk[g] = ppn[g];
    }
  } else {
    // ---------------- layer 1: units (2wg1, 2wg1+1); fused 1024-dot ----------------
    int wg1 = wg - 256;
    int ubase = wg1 * 2;
    float wi[8][8], wh[8][8], bb[8];
    #pragma unroll
    for (int rr = 0; rr < 8; rr++) {
      int g = rr >> 1, u = rr & 1;
      size_t grow = (size_t)(g * H_DIM + ubase + u);
      const float* si = w_ih1 + grow * H_DIM + lane * 8;
      const float* sh = w_hh1 + grow * H_DIM + lane * 8;
      float4 a = *(const float4*)(si);
      float4 b = *(const float4*)(si + 4);
      wi[rr][0] = a.x; wi[rr][1] = a.y; wi[rr][2] = a.z; wi[rr][3] = a.w;
      wi[rr][4] = b.x; wi[rr][5] = b.y; wi[rr][6] = b.z; wi[rr][7] = b.w;
      float4 c = *(const float4*)(sh);
      float4 e = *(const float4*)(sh + 4);
      wh[rr][0] = c.x; wh[rr][1] = c.y; wh[rr][2] = c.z; wh[rr][3] = c.w;
      wh[rr][4] = e.x; wh[rr][5] = e.y; wh[rr][6] = e.z; wh[rr][7] = e.w;
      bb[rr] = b_ih1[grow] + b_hh1[grow];
    }
    float c0 = 0.f, c1 = 0.f;

    for (int s = 0; s < N_NODES; s++) {
      float h0[8], h1[8];
      {
        const u64* b0 = hs0c + (size_t)(s & (RING - 1)) * 512 + lane * 8;
        const u64* b1 = hs1c + (size_t)((s - 1) & (RING - 1)) * 512 + lane * 8;
        u64 a0[8], a1[8]; int guard = 0;
        if (s > 0) {
          for (;;) {
            #pragma unroll
            for (int j = 0; j < 8; j++) a0[j] = ld_c8(b0 + j);
            #pragma unroll
            for (int j = 0; j < 8; j++) a1[j] = ld_c8(b1 + j);
            bool ok = true;
            #pragma unroll
            for (int j = 0; j < 8; j++) ok = ok && ((int)(a0[j] >> 32) == s + 1);
            #pragma unroll
            for (int j = 0; j < 8; j++) ok = ok && ((int)(a1[j] >> 32) == s);
            if (ok || ++guard > 50000000) break;
          }
          #pragma unroll
          for (int j = 0; j < 8; j++) { h0[j] = __uint_as_float((uint32)a0[j]); h1[j] = __uint_as_float((uint32)a1[j]); }
        } else {
          for (;;) {
            #pragma unroll
            for (int j = 0; j < 8; j++) a0[j] = ld_c8(b0 + j);
            bool ok = true;
            #pragma unroll
            for (int j = 0; j < 8; j++) ok = ok && ((int)(a0[j] >> 32) == 1);
            if (ok || ++guard > 50000000) break;
          }
          #pragma unroll
          for (int j = 0; j < 8; j++) { h0[j] = __uint_as_float((uint32)a0[j]); h1[j] = 0.f; }
        }
      }
      float d[8];
      #pragma unroll
      for (int rr = 0; rr < 8; rr++) {
        float acc = 0.f;
        #pragma unroll
        for (int j = 0; j < 8; j++) acc += wi[rr][j] * h0[j];
        #pragma unroll
        for (int j = 0; j < 8; j++) acc += wh[rr][j] * h1[j];
        d[rr] = acc;
      }
      #pragma unroll
      for (int rr = 0; rr < 8; rr++) {
        #pragma unroll
        for (int off = 1; off < 64; off <<= 1) d[rr] += __shfl_xor(d[rr], off, 64);
      }
      float h0v, h1v;
      {
        float ii = sigmoid_f(d[0] + bb[0]);
        float ff = sigmoid_f(d[2] + bb[2]);
        float g2 = tanh_f(d[4] + bb[4]);
        float oo = sigmoid_f(d[6] + bb[6]);
        c0 = ff * c0 + ii * g2;
        h0v = oo * tanh_f(c0);
      }
      {
        float ii = sigmoid_f(d[1] + bb[1]);
        float ff = sigmoid_f(d[3] + bb[3]);
        float g2 = tanh_f(d[5] + bb[5]);
        float oo = sigmoid_f(d[7] + bb[7]);
        c1 = ff * c1 + ii * g2;
        h1v = oo * tanh_f(c1);
      }
      if (lane < 2) {
        float hv = lane ? h1v : h0v;
        st_c8(hs1c + (size_t)(s & (RING - 1)) * 512 + ubase + lane, hv, s + 1);
        hs1p[(size_t)s * H_DIM + ubase + lane] = hv;     // plain store for k_fc
        if (s == N_NODES - 1) {
          dout[10512 + ubase + lane] = hv;
          dout[11536 + ubase + lane] = lane ? c1 : c0;
        }
      }
      if (lane == 0)
        __hip_atomic_store(&flags1[wg1], s + 1, __ATOMIC_RELAXED, __HIP_MEMORY_SCOPE_AGENT);
    }
  }
}

// ---------- fc head ----------
__global__ __launch_bounds__(256) void k_fc(const float* hs1, const float* fc_w,
                                            const float* fc_b, float* dout) {
  int row = blockIdx.x * 4 + (threadIdx.x >> 6);
  int lane = threadIdx.x & 63;
  float acc = 0.f;
  #pragma unroll
  for (int j = 0; j < 8; j++) {
    int c = lane + 64 * j;
    acc += hs1[(size_t)row * H_DIM + c] * fc_w[c];
  }
  for (int d = 32; d; d >>= 1) acc += __shfl_xor(acc, d, 64);
  if (lane == 0) dout[row] = acc + fc_b[0];
}

extern "C" void kernel_launch(void* const* d_in, const int* in_sizes, int n_in,
                              void* d_out, int out_size, void* d_ws, size_t ws_size,
                              hipStream_t stream) {
  const float* x     = (const float*)d_in[0];
  const int*   eb    = (const int*)d_in[1];
  const float* w1    = (const float*)d_in[2];
  const float* b1    = (const float*)d_in[3];
  const float* w2    = (const float*)d_in[4];
  const float* b2    = (const float*)d_in[5];
  const float* gamma = (const float*)d_in[6];
  const float* beta  = (const float*)d_in[7];
  const float* w_ih0 = (const float*)d_in[8];
  const float* w_hh0 = (const float*)d_in[9];
  const float* b_ih0 = (const float*)d_in[10];
  const float* b_hh0 = (const float*)d_in[11];
  const float* w_ih1 = (const float*)d_in[12];
  const float* w_hh1 = (const float*)d_in[13];
  const float* b_ih1 = (const float*)d_in[14];
  const float* b_hh1 = (const float*)d_in[15];
  const float* fc_w  = (const float*)d_in[16];
  const float* fc_b  = (const float*)d_in[17];
  float* dout = (float*)d_out;
  char* ws = (char*)d_ws;

  // ---- workspace layout (bytes); total ~82.5 MB ----
  int*    ctrl     = (int*)(ws + 0);
  int*    flags1   = (int*)(ws + 1024);         // 256 ints (layer1 progress)
  float*  colsum   = (float*)(ws + 4096);       // 512 floats
  float*  colsumsq = (float*)(ws + 6144);       // 512 floats
  int*    deg      = (int*)(ws + 8192);         // 10000 ints -> ends 48192 < 57344 (zero region)
  u64*    hs0c     = (u64*)(ws + 65536);        // ring [64][512] 8B chunks = 256 KB
  u64*    hs1c     = (u64*)(ws + 327680);       // ring [64][512] 8B chunks = 256 KB
  float*  y1       = (float*)(ws + 589824);     // [10000,512]; reused as hs1_plain
  float*  y2       = (float*)(ws + 21069824);   // [10000,512]
  float*  h0       = y2;                        // GIN h0 [10000,256] aliases y2
  ushort_t* pre0   = (ushort_t*)(ws + 41549824);// [10000,2048] bf16 -> ends 82509824
  // transient CSR scratch inside pre0's slot (dead before GEMM3 writes pre0):
  int*    off      = (int*)(ws + 41549824);     // 10001 ints
  int*    cursor   = (int*)(ws + 41589828);     // 10000 ints
  int*    csr      = (int*)(ws + 41629828);     // 640000 ints (ends 44189828)
  float*  hs1p     = y1;

  k_zero<<<56, 256, 0, stream>>>((int*)ws);
  k_detect<<<1, 64, 0, stream>>>(eb, ctrl);
  k_count<<<2500, 256, 0, stream>>>(eb, ctrl, deg);
  k_prefix<<<1, 1024, 0, stream>>>(deg, off, cursor);
  k_fill<<<2500, 256, 0, stream>>>(eb, ctrl, cursor, csr);
  k_agg<<<10000, 256, 0, stream>>>(x, off, csr, h0);

  dim3 g1(157, 8);
  k_gemm<256, true,  false, false><<<g1, 256, 0, stream>>>(h0, w1, b1, nullptr, y1, N_NODES, 512);
  dim3 g2(157, 8);
  k_gemm<512, false, false, false><<<g2, 256, 0, stream>>>(y1, w2, b2, nullptr, y2, N_NODES, 512);

  k_bnstats<<<157, 256, 0, stream>>>(y2, colsum, colsumsq);
  k_bnfin<<<2, 256, 0, stream>>>(colsum, colsumsq, gamma, beta);
  k_bnapply<<<20000, 256, 0, stream>>>(y2, colsum, colsumsq);

  dim3 g3(157, 32);
  k_gemm<512, false, true, true><<<g3, 256, 0, stream>>>(y2, w_ih0, b_ih0, b_hh0, pre0, N_NODES, 2048);

  k_lstm<<<512, 64, 0, stream>>>(pre0, w_hh0, w_ih1, w_hh1, b_ih1, b_hh1,
                                 hs0c, hs1c, hs1p, flags1, dout);
  k_fc<<<2500, 256, 0, stream>>>(hs1p, fc_w, fc_b, dout);
}

// Round 7
// 33583.881 us; speedup vs baseline: 1.1516x; 1.1516x over previous
//
#include <hip/hip_runtime.h>
#include <stdint.h>

#define N_NODES 10000
#define E_EDGES 640000
#define D_IN    256
#define H_DIM   512
#define K0      64    // layer0 workgroups (8 units each; wave = 2 units)
#define K1      128   // layer1 workgroups (4 units each; wave = 1 unit)
#define RING    64    // chunk ring depth (steps)

typedef unsigned short ushort_t;
typedef unsigned int   uint32;
typedef unsigned long long u64;

// ---------- bf16 helpers (pre0 internal storage only) ----------
__device__ __forceinline__ float bf2f(ushort_t u) {
  union { uint32 i; float f; } v; v.i = ((uint32)u) << 16; return v.f;
}
__device__ __forceinline__ ushort_t f2bf(float f) {
  union { float f; uint32 i; } v; v.f = f;
  uint32 x = v.i;
  uint32 r = (x + 0x7FFFu + ((x >> 16) & 1u)) >> 16;
  return (ushort_t)r;
}

// ---------- fast gate math ----------
__device__ __forceinline__ float sigmoid_f(float x) {
  return 1.f / (1.f + __expf(-x));
}
__device__ __forceinline__ float tanh_f(float x) {
  x = fminf(10.f, fmaxf(-10.f, x));
  float e2 = __expf(2.f * x);
  return (e2 - 1.f) / (e2 + 1.f);
}

// ---------- fused data+flag 8B chunks: [h fp32 | step+1] via relaxed agent atomics ----------
__device__ __forceinline__ u64 ld_c8(const u64* p) {
  return __hip_atomic_load(p, __ATOMIC_RELAXED, __HIP_MEMORY_SCOPE_AGENT);
}
__device__ __forceinline__ void st_c8(u64* p, float h, int flag) {
  u64 u = ((u64)(uint32)flag << 32) | (u64)__float_as_uint(h);
  __hip_atomic_store(p, u, __ATOMIC_RELAXED, __HIP_MEMORY_SCOPE_AGENT);
}

// ---------- workspace zero (control region only: 57344 B) ----------
__global__ void k_zero(int* p) {
  p[blockIdx.x * 256 + threadIdx.x] = 0;   // 56 blocks -> 14336 words
}

// ---------- edge_index dtype detector ----------
__global__ void k_detect(const int* eb, int* ctrl) {
  int v = eb[2 * (int)threadIdx.x + 1];
  if (v != 0) atomicOr(ctrl, 1);           // 1 => int32, 0 => int64
}

__device__ __forceinline__ int edge_src(const int* eb, int flag, int e) {
  return flag ? eb[e] : eb[2 * e];
}
__device__ __forceinline__ int edge_dst(const int* eb, int flag, int e) {
  return flag ? eb[E_EDGES + e] : eb[2 * (E_EDGES + e)];
}

// ---------- GIN: degree count ----------
__global__ __launch_bounds__(256) void k_count(const int* eb, const int* ctrl, int* deg) {
  int e = blockIdx.x * 256 + threadIdx.x;
  if (e >= E_EDGES) return;
  int flag = ctrl[0];
  atomicAdd(&deg[edge_dst(eb, flag, e)], 1);
}

// ---------- GIN: exclusive prefix sum ----------
__global__ __launch_bounds__(1024) void k_prefix(const int* deg, int* off, int* cursor) {
  __shared__ int sums[1024];
  int tid = threadIdx.x;
  const int PER = 10;
  int base = tid * PER;
  int loc[PER];
  int s = 0;
  for (int i = 0; i < PER; i++) {
    int idx = base + i;
    int v = (idx < N_NODES) ? deg[idx] : 0;
    loc[i] = s; s += v;
  }
  sums[tid] = s;
  __syncthreads();
  for (int d = 1; d < 1024; d <<= 1) {
    int v = (tid >= d) ? sums[tid - d] : 0;
    __syncthreads();
    sums[tid] += v;
    __syncthreads();
  }
  int excl = (tid == 0) ? 0 : sums[tid - 1];
  for (int i = 0; i < PER; i++) {
    int idx = base + i;
    if (idx < N_NODES) { int o = excl + loc[i]; off[idx] = o; cursor[idx] = o; }
  }
  if (tid == 1023) off[N_NODES] = sums[1023];
}

// ---------- GIN: CSR fill ----------
__global__ __launch_bounds__(256) void k_fill(const int* eb, const int* ctrl, int* cursor, int* csr) {
  int e = blockIdx.x * 256 + threadIdx.x;
  if (e >= E_EDGES) return;
  int flag = ctrl[0];
  int d = edge_dst(eb, flag, e);
  int s = edge_src(eb, flag, e);
  int slot = atomicAdd(&cursor[d], 1);
  csr[slot] = s;
}

// ---------- GIN: aggregate ----------
__global__ __launch_bounds__(256) void k_agg(const float* x, const int* off, const int* csr, float* h0) {
  int node = blockIdx.x;
  int f = threadIdx.x;
  float acc = x[(size_t)node * D_IN + f];
  int a = off[node], b = off[node + 1];
  for (int e = a; e < b; e++) {
    int s = csr[e];
    acc += x[(size_t)s * D_IN + f];
  }
  h0[(size_t)node * D_IN + f] = acc;
}

// ---------- fp32 tiled GEMM ----------
template<int KTOT, bool RELU, bool OUTBF16, bool TWOBIAS>
__global__ __launch_bounds__(256) void k_gemm(const float* __restrict__ A,
                                              const float* __restrict__ W,
                                              const float* __restrict__ bias1,
                                              const float* __restrict__ bias2,
                                              void* __restrict__ Cout, int M, int Ncols) {
  __shared__ float As[16][65];
  __shared__ float Ws[16][65];
  int tid = threadIdx.x;
  int tx = tid & 15, ty = tid >> 4;
  int by = blockIdx.x, bn = blockIdx.y;
  int lr  = tid >> 2;
  int lk4 = (tid & 3) * 4;
  float acc[4][4];
  #pragma unroll
  for (int i = 0; i < 4; i++)
    #pragma unroll
    for (int j = 0; j < 4; j++) acc[i][j] = 0.f;

  for (int k0 = 0; k0 < KTOT; k0 += 16) {
    int arow = by * 64 + lr;
    float4 av = make_float4(0.f, 0.f, 0.f, 0.f);
    if (arow < M) av = *(const float4*)(A + (size_t)arow * KTOT + k0 + lk4);
    As[lk4 + 0][lr] = av.x; As[lk4 + 1][lr] = av.y;
    As[lk4 + 2][lr] = av.z; As[lk4 + 3][lr] = av.w;
    float4 wv = *(const float4*)(W + (size_t)(bn * 64 + lr) * KTOT + k0 + lk4);
    Ws[lk4 + 0][lr] = wv.x; Ws[lk4 + 1][lr] = wv.y;
    Ws[lk4 + 2][lr] = wv.z; Ws[lk4 + 3][lr] = wv.w;
    __syncthreads();
    #pragma unroll
    for (int k = 0; k < 16; k++) {
      float a0 = As[k][ty], a1 = As[k][16 + ty], a2 = As[k][32 + ty], a3 = As[k][48 + ty];
      float w0 = Ws[k][tx], w1 = Ws[k][16 + tx], w2 = Ws[k][32 + tx], w3 = Ws[k][48 + tx];
      acc[0][0] += a0 * w0; acc[0][1] += a0 * w1; acc[0][2] += a0 * w2; acc[0][3] += a0 * w3;
      acc[1][0] += a1 * w0; acc[1][1] += a1 * w1; acc[1][2] += a1 * w2; acc[1][3] += a1 * w3;
      acc[2][0] += a2 * w0; acc[2][1] += a2 * w1; acc[2][2] += a2 * w2; acc[2][3] += a2 * w3;
      acc[3][0] += a3 * w0; acc[3][1] += a3 * w1; acc[3][2] += a3 * w2; acc[3][3] += a3 * w3;
    }
    __syncthreads();
  }
  float* Cf = (float*)Cout;
  ushort_t* Cb = (ushort_t*)Cout;
  #pragma unroll
  for (int i = 0; i < 4; i++) {
    int row = by * 64 + 16 * i + ty;
    if (row >= M) continue;
    #pragma unroll
    for (int j = 0; j < 4; j++) {
      int col = bn * 64 + 16 * j + tx;
      float b = bias1[col];
      if (TWOBIAS) b += bias2[col];
      float v = acc[i][j] + b;
      if (RELU) v = fmaxf(v, 0.f);
      if (OUTBF16) Cb[(size_t)row * Ncols + col] = f2bf(v);
      else         Cf[(size_t)row * Ncols + col] = v;
    }
  }
}

// ---------- BatchNorm ----------
__global__ __launch_bounds__(256) void k_bnstats(const float* y2, float* colsum, float* colsumsq) {
  int b = blockIdx.x, tid = threadIdx.x;
  int r0 = b * 64, r1 = min(r0 + 64, N_NODES);
  float s0 = 0, q0 = 0, s1 = 0, q1 = 0;
  for (int r = r0; r < r1; r++) {
    float v0 = y2[(size_t)r * H_DIM + tid];
    float v1 = y2[(size_t)r * H_DIM + tid + 256];
    s0 += v0; q0 += v0 * v0; s1 += v1; q1 += v1 * v1;
  }
  atomicAdd(&colsum[tid], s0);        atomicAdd(&colsumsq[tid], q0);
  atomicAdd(&colsum[tid + 256], s1);  atomicAdd(&colsumsq[tid + 256], q1);
}

__global__ __launch_bounds__(256) void k_bnfin(float* colsum, float* colsumsq,
                                               const float* gamma, const float* beta) {
  int c = blockIdx.x * 256 + threadIdx.x;
  if (c >= H_DIM) return;
  float mean = colsum[c] * (1.f / N_NODES);
  float var  = colsumsq[c] * (1.f / N_NODES) - mean * mean;
  float sc = gamma[c] * rsqrtf(var + 1e-5f);
  float sh = beta[c] - mean * sc;
  colsum[c] = sc; colsumsq[c] = sh;
}

__global__ __launch_bounds__(256) void k_bnapply(float* y2, const float* sc, const float* sh) {
  size_t i = (size_t)blockIdx.x * 256 + threadIdx.x;
  int c = (int)(i & (H_DIM - 1));
  float v = y2[i] * sc[c] + sh[c];
  y2[i] = v > 0.f ? v : 0.f;
}

// ---------- persistent 2-layer LSTM scan: one barrier/step, wave-autonomous units ----------
// 192 WGs x 256 threads. Staging: all threads poll fused [h|step] chunks into
// double-buffered LDS, one __syncthreads, then each WAVE computes complete
// units (dot + butterfly reduce + gather shuffles + gates) and publishes its
// chunks immediately -- no second barrier, no wave-0 serialization.
__global__ __launch_bounds__(256, 1) void k_lstm(const ushort_t* pre0, const float* w_hh0,
                                              const float* w_ih1, const float* w_hh1,
                                              const float* b_ih1, const float* b_hh1,
                                              u64* hs0c, u64* hs1c, float* hs1p,
                                              int* flags1, float* dout) {
  __shared__ float lds_h[2][1024];   // layer0 uses [.][0..512); layer1 [h0|h1] concat
  int tid = threadIdx.x;
  int wave = tid >> 6, lane = tid & 63;
  int wg = blockIdx.x;

  if (wg < K0) {
    // ---- layer 0: WG owns units [wg*8, wg*8+8); wave owns 2 units ----
    int u_w = wg * 8 + wave * 2;        // wave's first unit
    int rr = lane >> 3, kp = lane & 7;  // row rr = 2*gate + u; segment kp (64 elems)
    int g_r = rr >> 1, u_r = rr & 1;
    float w_reg[64];
    {
      const float* src = w_hh0 + (size_t)(g_r * H_DIM + u_w + u_r) * H_DIM + kp * 64;
      #pragma unroll
      for (int i = 0; i < 16; i++) {
        int j0 = ((i + 2 * kp) & 15) * 4;      // bank stagger (measured conflict-free)
        float4 v = *(const float4*)(src + j0);
        w_reg[4*i+0]=v.x; w_reg[4*i+1]=v.y; w_reg[4*i+2]=v.z; w_reg[4*i+3]=v.w;
      }
    }
    int myu = u_w + (lane & 1);         // unit this lane's gate math tracks
    float ppk[4];                       // pre-activations for step t (prefetched)
    #pragma unroll
    for (int g = 0; g < 4; g++)
      ppk[g] = bf2f(pre0[(size_t)0 * 2048 + g * H_DIM + myu]);
    float c_reg = 0.f;

    for (int t = 0; t < N_NODES; t++) {
      float* Lh = lds_h[t & 1];
      if (t > 0) {
        const u64* pa = hs0c + (size_t)((t-1) & (RING-1)) * 512 + tid;
        const u64* pb = pa + 256;
        u64 ua, ub; int guard = 0;
        for (;;) {
          ua = ld_c8(pa); ub = ld_c8(pb);
          if (((int)(ua>>32) == t && (int)(ub>>32) == t) || ++guard > 100000000) break;
        }
        Lh[tid]       = __uint_as_float((uint32)ua);
        Lh[tid + 256] = __uint_as_float((uint32)ub);
      }
      __syncthreads();                                  // the ONLY barrier per step
      // prefetch next step's pre-acts (drains at next barrier, a full step later)
      float ppn[4];
      if (t + 1 < N_NODES) {
        #pragma unroll
        for (int g = 0; g < 4; g++)
          ppn[g] = bf2f(pre0[(size_t)(t+1) * 2048 + g * H_DIM + myu]);
      } else { ppn[0]=ppn[1]=ppn[2]=ppn[3]=0.f; }
      // amortized ring back-pressure vs layer1 consume-progress
      if ((t & 31) == 0 && t >= 32 && tid < K1) {
        int tgt = t - 31, guard = 0;
        while (__hip_atomic_load(&flags1[tid], __ATOMIC_RELAXED, __HIP_MEMORY_SCOPE_AGENT) < tgt) {
          __builtin_amdgcn_s_sleep(2);
          if (++guard > 50000000) break;
        }
      }
      float d = 0.f;
      if (t > 0) {
        const float* hrow = Lh + kp * 64;
        #pragma unroll
        for (int i = 0; i < 16; i++) {
          int j0 = ((i + 2 * kp) & 15) * 4;             // matches weight stagger
          float4 h4 = *(const float4*)(hrow + j0);
          d += w_reg[4*i]*h4.x + w_reg[4*i+1]*h4.y + w_reg[4*i+2]*h4.z + w_reg[4*i+3]*h4.w;
        }
        d += __shfl_xor(d, 1, 64);
        d += __shfl_xor(d, 2, 64);
        d += __shfl_xor(d, 4, 64);                      // all 8 lanes of row hold dot
      }
      int u = lane & 1;
      float gi = __shfl(d, 8 * u, 64)      + ppk[0];
      float gf = __shfl(d, 16 + 8 * u, 64) + ppk[1];
      float gg = __shfl(d, 32 + 8 * u, 64) + ppk[2];
      float go = __shfl(d, 48 + 8 * u, 64) + ppk[3];
      float ii = sigmoid_f(gi), ff = sigmoid_f(gf), gz = tanh_f(gg), oo = sigmoid_f(go);
      c_reg = ff * c_reg + ii * gz;
      float hv = oo * tanh_f(c_reg);
      if (lane < 2) {
        st_c8(hs0c + (size_t)(t & (RING-1)) * 512 + myu, hv, t + 1);
        if (t == N_NODES - 1) {
          dout[10000 + myu] = hv;
          dout[11024 + myu] = c_reg;
        }
      }
      ppk[0]=ppn[0]; ppk[1]=ppn[1]; ppk[2]=ppn[2]; ppk[3]=ppn[3];
    }
  } else {
    // ---- layer 1: WG owns units [wg1*4, wg1*4+4); wave owns 1 unit (1024-dot) ----
    int wg1 = wg - K0;
    int unit = wg1 * 4 + wave;
    int g_r = lane >> 4, seg = lane & 15;   // row = gate g_r; 16 lanes/row, 64 elems each
    float w_reg[64];
    {
      size_t grow = (size_t)(g_r * H_DIM + unit);
      const float* base = (seg < 8) ? (w_ih1 + grow * H_DIM) : (w_hh1 + grow * H_DIM - 512);
      #pragma unroll
      for (int i = 0; i < 16; i++) {
        int j0 = ((i + seg) & 15) * 4;          // bank stagger (<=2-way)
        float4 v = *(const float4*)(base + seg * 64 + j0);
        w_reg[4*i+0]=v.x; w_reg[4*i+1]=v.y; w_reg[4*i+2]=v.z; w_reg[4*i+3]=v.w;
      }
    }
    float bb[4];
    #pragma unroll
    for (int g = 0; g < 4; g++) bb[g] = b_ih1[g * H_DIM + unit] + b_hh1[g * H_DIM + unit];
    float c_reg = 0.f;

    for (int s = 0; s < N_NODES; s++) {
      float* Lh = lds_h[s & 1];
      {
        const u64* p0a = hs0c + (size_t)(s & (RING-1)) * 512 + tid;
        const u64* p0b = p0a + 256;
        u64 ua, ub; int guard = 0;
        if (s > 0) {
          const u64* p1a = hs1c + (size_t)((s-1) & (RING-1)) * 512 + tid;
          const u64* p1b = p1a + 256;
          u64 va, vb;
          for (;;) {
            ua = ld_c8(p0a); ub = ld_c8(p0b); va = ld_c8(p1a); vb = ld_c8(p1b);
            bool ok = ((int)(ua>>32) == s+1) && ((int)(ub>>32) == s+1)
                   && ((int)(va>>32) == s)   && ((int)(vb>>32) == s);
            if (ok || ++guard > 100000000) break;
          }
          Lh[512 + tid]       = __uint_as_float((uint32)va);
          Lh[512 + tid + 256] = __uint_as_float((uint32)vb);
        } else {
          for (;;) {
            ua = ld_c8(p0a); ub = ld_c8(p0b);
            if (((int)(ua>>32) == 1 && (int)(ub>>32) == 1) || ++guard > 100000000) break;
          }
          Lh[512 + tid]       = 0.f;
          Lh[512 + tid + 256] = 0.f;
        }
        Lh[tid]       = __uint_as_float((uint32)ua);
        Lh[tid + 256] = __uint_as_float((uint32)ub);
      }
      __syncthreads();                                  // the ONLY barrier per step
      if (tid == 0)                                     // slot consumed (staged in LDS)
        __hip_atomic_store(&flags1[wg1], s + 1, __ATOMIC_RELAXED, __HIP_MEMORY_SCOPE_AGENT);
      float d = 0.f;
      {
        const float* hrow = Lh + seg * 64;
        #pragma unroll
        for (int i = 0; i < 16; i++) {
          int j0 = ((i + seg) & 15) * 4;                // matches weight stagger
          float4 h4 = *(const float4*)(hrow + j0);
          d += w_reg[4*i]*h4.x + w_reg[4*i+1]*h4.y + w_reg[4*i+2]*h4.z + w_reg[4*i+3]*h4.w;
        }
      }
      d += __shfl_xor(d, 1, 64);
      d += __shfl_xor(d, 2, 64);
      d += __shfl_xor(d, 4, 64);
      d += __shfl_xor(d, 8, 64);                        // all 16 lanes of row hold dot
      float gi = __shfl(d, 0, 64)  + bb[0];
      float gf = __shfl(d, 16, 64) + bb[1];
      float gg = __shfl(d, 32, 64) + bb[2];
      float go = __shfl(d, 48, 64) + bb[3];
      float ii = sigmoid_f(gi), ff = sigmoid_f(gf), gz = tanh_f(gg), oo = sigmoid_f(go);
      c_reg = ff * c_reg + ii * gz;
      float hv = oo * tanh_f(c_reg);
      if (lane == 0) {
        st_c8(hs1c + (size_t)(s & (RING-1)) * 512 + unit, hv, s + 1);
        hs1p[(size_t)s * H_DIM + unit] = hv;
        if (s == N_NODES - 1) {
          dout[10512 + unit] = hv;
          dout[11536 + unit] = c_reg;
        }
      }
    }
  }
}

// ---------- fc head ----------
__global__ __launch_bounds__(256) void k_fc(const float* hs1, const float* fc_w,
                                            const float* fc_b, float* dout) {
  int row = blockIdx.x * 4 + (threadIdx.x >> 6);
  int lane = threadIdx.x & 63;
  float acc = 0.f;
  #pragma unroll
  for (int j = 0; j < 8; j++) {
    int c = lane + 64 * j;
    acc += hs1[(size_t)row * H_DIM + c] * fc_w[c];
  }
  for (int d = 32; d; d >>= 1) acc += __shfl_xor(acc, d, 64);
  if (lane == 0) dout[row] = acc + fc_b[0];
}

extern "C" void kernel_launch(void* const* d_in, const int* in_sizes, int n_in,
                              void* d_out, int out_size, void* d_ws, size_t ws_size,
                              hipStream_t stream) {
  const float* x     = (const float*)d_in[0];
  const int*   eb    = (const int*)d_in[1];
  const float* w1    = (const float*)d_in[2];
  const float* b1    = (const float*)d_in[3];
  const float* w2    = (const float*)d_in[4];
  const float* b2    = (const float*)d_in[5];
  const float* gamma = (const float*)d_in[6];
  const float* beta  = (const float*)d_in[7];
  const float* w_ih0 = (const float*)d_in[8];
  const float* w_hh0 = (const float*)d_in[9];
  const float* b_ih0 = (const float*)d_in[10];
  const float* b_hh0 = (const float*)d_in[11];
  const float* w_ih1 = (const float*)d_in[12];
  const float* w_hh1 = (const float*)d_in[13];
  const float* b_ih1 = (const float*)d_in[14];
  const float* b_hh1 = (const float*)d_in[15];
  const float* fc_w  = (const float*)d_in[16];
  const float* fc_b  = (const float*)d_in[17];
  float* dout = (float*)d_out;
  char* ws = (char*)d_ws;

  // ---- workspace layout (bytes); total ~82.5 MB ----
  int*    ctrl     = (int*)(ws + 0);
  int*    flags1   = (int*)(ws + 1024);         // 128 ints (layer1 consume progress)
  float*  colsum   = (float*)(ws + 4096);       // 512 floats
  float*  colsumsq = (float*)(ws + 6144);       // 512 floats
  int*    deg      = (int*)(ws + 8192);         // 10000 ints -> ends 48192 < 57344 (zero region)
  u64*    hs0c     = (u64*)(ws + 65536);        // ring [64][512] 8B chunks = 256 KB
  u64*    hs1c     = (u64*)(ws + 327680);       // ring [64][512] 8B chunks = 256 KB
  float*  y1       = (float*)(ws + 589824);     // [10000,512]; reused as hs1_plain
  float*  y2       = (float*)(ws + 21069824);   // [10000,512]
  float*  h0       = y2;                        // GIN h0 [10000,256] aliases y2
  ushort_t* pre0   = (ushort_t*)(ws + 41549824);// [10000,2048] bf16 -> ends 82509824
  // transient CSR scratch inside pre0's slot (dead before GEMM3 writes pre0):
  int*    off      = (int*)(ws + 41549824);     // 10001 ints
  int*    cursor   = (int*)(ws + 41589828);     // 10000 ints
  int*    csr      = (int*)(ws + 41629828);     // 640000 ints (ends 44189828)
  float*  hs1p     = y1;

  k_zero<<<56, 256, 0, stream>>>((int*)ws);
  k_detect<<<1, 64, 0, stream>>>(eb, ctrl);
  k_count<<<2500, 256, 0, stream>>>(eb, ctrl, deg);
  k_prefix<<<1, 1024, 0, stream>>>(deg, off, cursor);
  k_fill<<<2500, 256, 0, stream>>>(eb, ctrl, cursor, csr);
  k_agg<<<10000, 256, 0, stream>>>(x, off, csr, h0);

  dim3 g1(157, 8);
  k_gemm<256, true,  false, false><<<g1, 256, 0, stream>>>(h0, w1, b1, nullptr, y1, N_NODES, 512);
  dim3 g2(157, 8);
  k_gemm<512, false, false, false><<<g2, 256, 0, stream>>>(y1, w2, b2, nullptr, y2, N_NODES, 512);

  k_bnstats<<<157, 256, 0, stream>>>(y2, colsum, colsumsq);
  k_bnfin<<<2, 256, 0, stream>>>(colsum, colsumsq, gamma, beta);
  k_bnapply<<<20000, 256, 0, stream>>>(y2, colsum, colsumsq);

  dim3 g3(157, 32);
  k_gemm<512, false, true, true><<<g3, 256, 0, stream>>>(y2, w_ih0, b_ih0, b_hh0, pre0, N_NODES, 2048);

  k_lstm<<<192, 256, 0, stream>>>(pre0, w_hh0, w_ih1, w_hh1, b_ih1, b_hh1,
                                  hs0c, hs1c, hs1p, flags1, dout);
  k_fc<<<2500, 256, 0, stream>>>(hs1p, fc_w, fc_b, dout);
}